// Round 3
// baseline (175.529 us; speedup 1.0000x reference)
//
#include <hip/hip_runtime.h>
#include <hip/hip_bf16.h>
#include <cstdint>
#include <cstddef>

// Problem constants (x = (8192, 768) fp32)
#define GN 8192
#define GD 768
#define NB 64            // 128-row blocks
#define NTILE 2080       // NB*(NB+1)/2 triangular tiles
#define KSTEPS 24        // 768 / 32

typedef __attribute__((ext_vector_type(8))) short bf16x8;  // 8 bf16 = 4 VGPRs
typedef __attribute__((ext_vector_type(4))) float f32x4;

typedef __attribute__((address_space(1))) const unsigned int gu32;
typedef __attribute__((address_space(3))) unsigned int lu32;

__device__ __forceinline__ void gl2lds16(const void* g, void* l) {
    // async global->LDS, 16B per lane; LDS dest is wave-uniform base + lane*16
    __builtin_amdgcn_global_load_lds((gu32*)g, (lu32*)l, 16, 0, 0);
}

// swizzled LDS byte offset for (row, 16B-kblock): 64B rows paired into 128B
// super-rows; kblock XOR'd by (superrow&7) -> 2-way-max bank aliasing (free)
__device__ __forceinline__ int swz(int r, int kb) {
    return ((r >> 1) << 7) + (((((r & 1) << 2) | kb) ^ ((r >> 1) & 7)) << 4);
}

// ---------------- Kernel 1: bf16 cast + row sum-of-squares ----------------
// One wave per row; float4 loads, ushort4 bf16 stores, shuffle reduce. Grid 2048.
__global__ __launch_bounds__(256) void prep_kernel(const float* __restrict__ x,
                                                   __hip_bfloat16* __restrict__ xb,
                                                   float* __restrict__ sq) {
    const int w = threadIdx.x >> 6, lane = threadIdx.x & 63;
    const int row = blockIdx.x * 4 + w;
    const float4* xr = (const float4*)(x + (size_t)row * GD);
    ushort4* xbr = (ushort4*)(xb + (size_t)row * GD);
    float s = 0.f;
#pragma unroll
    for (int i = 0; i < 3; ++i) {
        float4 v = xr[lane + 64 * i];
        s += v.x * v.x + v.y * v.y + v.z * v.z + v.w * v.w;
        __hip_bfloat16 a = __float2bfloat16(v.x), b = __float2bfloat16(v.y),
                       c = __float2bfloat16(v.z), d = __float2bfloat16(v.w);
        ushort4 o;
        o.x = *(const unsigned short*)&a;
        o.y = *(const unsigned short*)&b;
        o.z = *(const unsigned short*)&c;
        o.w = *(const unsigned short*)&d;
        xbr[lane + 64 * i] = o;
    }
#pragma unroll
    for (int off = 1; off < 64; off <<= 1) s += __shfl_xor(s, off);
    if (lane == 0) sq[row] = s;
}

// ------- Kernel 2: symmetric triangular tile GEMM + entropy, double-buffered -------
// One 128x128 tile (I,J), J<=I, per WG. 4 waves stacked in M (32 rows x 128 cols
// each). Single barrier per K-iter; prefetch of k+1 issued right after the
// barrier so it overlaps the ds_read+MFMA phase (intra-block latency hiding).
// C/D layout: col=lane&15, row=(lane>>4)*4+reg.
__global__ __launch_bounds__(256, 3) void sym_gemm_entropy(
    const __hip_bfloat16* __restrict__ xb, const float* __restrict__ sq,
    const float* __restrict__ taup, float* __restrict__ pm,
    float* __restrict__ ps, float* __restrict__ pt) {
    __shared__ __align__(16) char As[2][8192];
    __shared__ __align__(16) char Bs[2][8192];
    __shared__ float tmrg[128][4][3];

    const int tid = threadIdx.x;
    const int lane = tid & 63;
    const int w = tid >> 6;
    const int quad = lane >> 4, cl = lane & 15;

    const int b = blockIdx.x;
    int I = (int)((sqrtf(8.0f * (float)b + 1.0f) - 1.0f) * 0.5f);
    while ((I + 1) * (I + 2) / 2 <= b) ++I;
    while (I * (I + 1) / 2 > b) --I;
    const int J = b - I * (I + 1) / 2;
    const int row_base = I * 128;
    const int col_base = J * 128;
    const float tau = *taup;

    // staging decode: thread t stages LDS offset t*16; pick the global
    // (row, kblock) that belongs at that swizzled slot
    const int bb = (tid & 7) ^ ((tid >> 3) & 7);
    const int sRow = ((tid >> 3) << 1) | (bb >> 2);  // 0..63
    const int sKb = bb & 3;
    const __hip_bfloat16* gA0 = xb + (size_t)(row_base + sRow) * GD + sKb * 8;
    const __hip_bfloat16* gA1 = gA0 + (size_t)64 * GD;
    const __hip_bfloat16* gB0 = xb + (size_t)(col_base + sRow) * GD + sKb * 8;
    const __hip_bfloat16* gB1 = gB0 + (size_t)64 * GD;

    int offA[2], offB[8];
#pragma unroll
    for (int ti = 0; ti < 2; ++ti) offA[ti] = swz(w * 32 + ti * 16 + cl, quad);
#pragma unroll
    for (int tj = 0; tj < 8; ++tj) offB[tj] = swz(tj * 16 + cl, quad);

    f32x4 acc[2][8];
#pragma unroll
    for (int i = 0; i < 2; ++i)
#pragma unroll
        for (int j = 0; j < 8; ++j) acc[i][j] = (f32x4){0.f, 0.f, 0.f, 0.f};

    // prologue: stage k=0 into buffer 0
    gl2lds16(gA0, As[0] + tid * 16);
    gl2lds16(gA1, As[0] + 4096 + tid * 16);
    gl2lds16(gB0, Bs[0] + tid * 16);
    gl2lds16(gB1, Bs[0] + 4096 + tid * 16);

    for (int kk = 0; kk < KSTEPS; ++kk) {
        __syncthreads();  // drains vmcnt: buf[kk&1] valid; prior buf reads done
        if (kk + 1 < KSTEPS) {
            const int k1 = (kk + 1) * 32;  // bf16 elements
            char* a = As[(kk + 1) & 1];
            char* bs = Bs[(kk + 1) & 1];
            gl2lds16(gA0 + k1, a + tid * 16);
            gl2lds16(gA1 + k1, a + 4096 + tid * 16);
            gl2lds16(gB0 + k1, bs + tid * 16);
            gl2lds16(gB1 + k1, bs + 4096 + tid * 16);
        }
        const char* ab = As[kk & 1];
        const char* bbuf = Bs[kk & 1];
        bf16x8 af[2], bfv[8];
#pragma unroll
        for (int ti = 0; ti < 2; ++ti) af[ti] = *(const bf16x8*)(ab + offA[ti]);
#pragma unroll
        for (int tj = 0; tj < 8; ++tj) bfv[tj] = *(const bf16x8*)(bbuf + offB[tj]);
#pragma unroll
        for (int ti = 0; ti < 2; ++ti)
#pragma unroll
            for (int tj = 0; tj < 8; ++tj)
                acc[ti][tj] = __builtin_amdgcn_mfma_f32_16x16x32_bf16(
                    af[ti], bfv[tj], acc[ti][tj], 0, 0, 0);
    }

    // per-lane metadata
    float sqr[8];
    int rowg[8];
#pragma unroll
    for (int ti = 0; ti < 2; ++ti)
#pragma unroll
        for (int rg = 0; rg < 4; ++rg) {
            int r = row_base + w * 32 + ti * 16 + quad * 4 + rg;
            rowg[ti * 4 + rg] = r;
            sqr[ti * 4 + rg] = sq[r];
        }
    float sqc[8];
    int colg[8];
#pragma unroll
    for (int tj = 0; tj < 8; ++tj) {
        int c = col_base + tj * 16 + cl;
        colg[tj] = c;
        sqc[tj] = sq[c];
    }

    // ---- direct pass: one (m,S,T) per row of block I over J's 128 cols ----
#pragma unroll
    for (int ti = 0; ti < 2; ++ti)
#pragma unroll
        for (int rg = 0; rg < 4; ++rg) {
            const int idx = ti * 4 + rg;
            float vv[8];
            float mloc = -1e30f;
#pragma unroll
            for (int tj = 0; tj < 8; ++tj) {
                float pen = (rowg[idx] == colg[tj]) ? 100.f : 0.f;
                float v = tau * (2.f * acc[ti][tj][rg] - sqr[idx] - sqc[tj] - pen);
                vv[tj] = v;
                mloc = fmaxf(mloc, v);
            }
#pragma unroll
            for (int mk = 1; mk < 16; mk <<= 1) mloc = fmaxf(mloc, __shfl_xor(mloc, mk));
            float s = 0.f, t = 0.f;
#pragma unroll
            for (int tj = 0; tj < 8; ++tj) {
                float d = vv[tj] - mloc;
                float e = __expf(d);
                s += e;
                t += e * d;
            }
#pragma unroll
            for (int mk = 1; mk < 16; mk <<= 1) {
                s += __shfl_xor(s, mk);
                t += __shfl_xor(t, mk);
            }
            if (cl == 0) {
                int r = rowg[idx];
                pm[(size_t)J * GN + r] = mloc;
                ps[(size_t)J * GN + r] = s;
                pt[(size_t)J * GN + r] = t;
            }
        }

    // ---- transposed pass (off-diagonal tiles): rows of block J over I's rows ----
    if (I != J) {  // block-uniform branch
#pragma unroll
        for (int tj = 0; tj < 8; ++tj) {
            float vv[8];
            float mloc = -1e30f;
#pragma unroll
            for (int ti = 0; ti < 2; ++ti)
#pragma unroll
                for (int rg = 0; rg < 4; ++rg) {
                    float v = tau * (2.f * acc[ti][tj][rg] - sqr[ti * 4 + rg] - sqc[tj]);
                    vv[ti * 4 + rg] = v;
                    mloc = fmaxf(mloc, v);
                }
            mloc = fmaxf(mloc, __shfl_xor(mloc, 16));
            mloc = fmaxf(mloc, __shfl_xor(mloc, 32));
            float s = 0.f, t = 0.f;
#pragma unroll
            for (int k = 0; k < 8; ++k) {
                float d = vv[k] - mloc;
                float e = __expf(d);
                s += e;
                t += e * d;
            }
            s += __shfl_xor(s, 16);
            t += __shfl_xor(t, 16);
            s += __shfl_xor(s, 32);
            t += __shfl_xor(t, 32);
            if (quad == 0) {
                int c = tj * 16 + cl;
                tmrg[c][w][0] = mloc;
                tmrg[c][w][1] = s;
                tmrg[c][w][2] = t;
            }
        }
        __syncthreads();
        if (tid < 128) {
            float m = tmrg[tid][0][0], S = tmrg[tid][0][1], T = tmrg[tid][0][2];
#pragma unroll
            for (int ww = 1; ww < 4; ++ww) {
                float mc = tmrg[tid][ww][0], Sc = tmrg[tid][ww][1], Tc = tmrg[tid][ww][2];
                float mn = fmaxf(m, mc);
                float ea = __expf(m - mn), eb = __expf(mc - mn);
                T = (T + (m - mn) * S) * ea + (Tc + (mc - mn) * Sc) * eb;
                S = S * ea + Sc * eb;
                m = mn;
            }
            int c = col_base + tid;
            pm[(size_t)I * GN + c] = m;
            ps[(size_t)I * GN + c] = S;
            pt[(size_t)I * GN + c] = T;
        }
    }
}

// ---------------- Kernel 3: combine 64 slots -> row entropy -> block sums ----------------
__global__ __launch_bounds__(256) void combine(const float* __restrict__ pm,
                                               const float* __restrict__ ps,
                                               const float* __restrict__ pt,
                                               float* __restrict__ bsums) {
    const int row = blockIdx.x * 256 + threadIdx.x;
    float m = -1e30f, S = 0.f, T = 0.f;
    for (int c = 0; c < NB; ++c) {
        float mc = pm[(size_t)c * GN + row];
        float Sc = ps[(size_t)c * GN + row];
        float Tc = pt[(size_t)c * GN + row];
        float mn = fmaxf(m, mc);
        float ea = __expf(m - mn), eb = __expf(mc - mn);
        T = (T + (m - mn) * S) * ea + (Tc + (mc - mn) * Sc) * eb;
        S = S * ea + Sc * eb;
        m = mn;
    }
    float ent = __logf(S) - T / S;
#pragma unroll
    for (int off = 1; off < 64; off <<= 1) ent += __shfl_xor(ent, off);
    __shared__ float ls[4];
    if ((threadIdx.x & 63) == 0) ls[threadIdx.x >> 6] = ent;
    __syncthreads();
    if (threadIdx.x == 0) bsums[blockIdx.x] = ls[0] + ls[1] + ls[2] + ls[3];
}

// ---------------- Kernel 4: final scalar ----------------
__global__ __launch_bounds__(64) void finalize(const float* __restrict__ bsums,
                                               const float* __restrict__ coefp,
                                               float* __restrict__ out) {
    const int t = threadIdx.x;
    float v = (t < GN / 256) ? bsums[t] : 0.f;
#pragma unroll
    for (int off = 1; off < 64; off <<= 1) v += __shfl_xor(v, off);
    if (t == 0) out[0] = coefp[0] * v / (float)GN;
}

extern "C" void kernel_launch(void* const* d_in, const int* in_sizes, int n_in,
                              void* d_out, int out_size, void* d_ws, size_t ws_size,
                              hipStream_t stream) {
    const float* x = (const float*)d_in[0];      // 8192*768 fp32
    const float* coefp = (const float*)d_in[1];  // scalar
    const float* taup = (const float*)d_in[2];   // scalar
    float* out = (float*)d_out;

    char* ws = (char*)d_ws;
    __hip_bfloat16* xb = (__hip_bfloat16*)ws;            // 12,582,912 B
    float* sq = (float*)(ws + 12582912);                 // 32,768 B
    float* pm = (float*)(ws + 12615680);                 // 2,097,152 B
    float* ps = (float*)(ws + 12615680 + 2097152);       // 2,097,152 B
    float* pt = (float*)(ws + 12615680 + 2 * 2097152);   // 2,097,152 B
    float* bsums = (float*)(ws + 12615680 + 3 * 2097152);// 128 B

    prep_kernel<<<GN / 4, 256, 0, stream>>>(x, xb, sq);
    sym_gemm_entropy<<<NTILE, 256, 0, stream>>>(xb, sq, taup, pm, ps, pt);
    combine<<<GN / 256, 256, 0, stream>>>(pm, ps, pt, bsums);
    finalize<<<1, 64, 0, stream>>>(bsums, coefp, out);
}

// Round 4
// 165.593 us; speedup vs baseline: 1.0600x; 1.0600x over previous
//
#include <hip/hip_runtime.h>
#include <hip/hip_bf16.h>
#include <cstdint>
#include <cstddef>

// Problem constants (x = (8192, 768) fp32)
#define GN 8192
#define GD 768
#define NB 64            // 128-row blocks
#define NTILE 2080       // NB*(NB+1)/2 triangular tiles
#define KSTEPS 24        // 768 / 32

typedef __attribute__((ext_vector_type(8))) short bf16x8;  // 8 bf16 = 4 VGPRs
typedef __attribute__((ext_vector_type(4))) float f32x4;

typedef __attribute__((address_space(1))) const unsigned int gu32;
typedef __attribute__((address_space(3))) unsigned int lu32;

__device__ __forceinline__ void gl2lds16(const void* g, void* l) {
    // async global->LDS, 16B per lane; LDS dest is wave-uniform base + lane*16
    __builtin_amdgcn_global_load_lds((gu32*)g, (lu32*)l, 16, 0, 0);
}

// swizzled LDS byte offset for (row, 16B-kblock): 64B rows paired into 128B
// super-rows; kblock XOR'd by (superrow&7) -> 2-way-max bank aliasing (free)
__device__ __forceinline__ int swz(int r, int kb) {
    return ((r >> 1) << 7) + (((((r & 1) << 2) | kb) ^ ((r >> 1) & 7)) << 4);
}

// ---------------- Kernel 1: bf16 cast + row sum-of-squares (+ zero out) ----------------
__global__ __launch_bounds__(256) void prep_kernel(const float* __restrict__ x,
                                                   __hip_bfloat16* __restrict__ xb,
                                                   float* __restrict__ sq,
                                                   float* __restrict__ out) {
    if (blockIdx.x == 0 && threadIdx.x == 0) out[0] = 0.f;  // for combine's atomics
    const int w = threadIdx.x >> 6, lane = threadIdx.x & 63;
    const int row = blockIdx.x * 4 + w;
    const float4* xr = (const float4*)(x + (size_t)row * GD);
    ushort4* xbr = (ushort4*)(xb + (size_t)row * GD);
    float s = 0.f;
#pragma unroll
    for (int i = 0; i < 3; ++i) {
        float4 v = xr[lane + 64 * i];
        s += v.x * v.x + v.y * v.y + v.z * v.z + v.w * v.w;
        __hip_bfloat16 a = __float2bfloat16(v.x), b = __float2bfloat16(v.y),
                       c = __float2bfloat16(v.z), d = __float2bfloat16(v.w);
        ushort4 o;
        o.x = *(const unsigned short*)&a;
        o.y = *(const unsigned short*)&b;
        o.z = *(const unsigned short*)&c;
        o.w = *(const unsigned short*)&d;
        xbr[lane + 64 * i] = o;
    }
#pragma unroll
    for (int off = 1; off < 64; off <<= 1) s += __shfl_xor(s, off);
    if (lane == 0) sq[row] = s;
}

// ------- Kernel 2: symmetric triangular tile GEMM + entropy, double-buffered -------
// One 128x128 tile (I,J), J<=I, per WG. 4 waves stacked in M (32 rows x 128 cols).
// K-loop body order: barrier -> ds_read frags(buf k) -> issue prefetch(k+1)
// -> MFMA. Nothing reads LDS between the prefetch and the next barrier, so the
// only vmcnt(0) drain is at the barrier, covered by the ds_read+MFMA phase.
// C/D layout: col=lane&15, row=(lane>>4)*4+reg.
__global__ __launch_bounds__(256, 3) void sym_gemm_entropy(
    const __hip_bfloat16* __restrict__ xb, const float* __restrict__ sq,
    const float* __restrict__ taup, float* __restrict__ pm,
    float* __restrict__ ps, float* __restrict__ pt) {
    __shared__ __align__(16) char As[2][8192];
    __shared__ __align__(16) char Bs[2][8192];
    __shared__ float tmrg[128][4][3];

    const int tid = threadIdx.x;
    const int lane = tid & 63;
    const int w = tid >> 6;
    const int quad = lane >> 4, cl = lane & 15;

    const int b = blockIdx.x;
    int I = (int)((sqrtf(8.0f * (float)b + 1.0f) - 1.0f) * 0.5f);
    while ((I + 1) * (I + 2) / 2 <= b) ++I;
    while (I * (I + 1) / 2 > b) --I;
    const int J = b - I * (I + 1) / 2;
    const int row_base = I * 128;
    const int col_base = J * 128;
    const float tau = *taup;

    // staging decode: thread t stages LDS offset t*16; pick the global
    // (row, kblock) that belongs at that swizzled slot
    const int bb = (tid & 7) ^ ((tid >> 3) & 7);
    const int sRow = ((tid >> 3) << 1) | (bb >> 2);  // 0..63
    const int sKb = bb & 3;
    const __hip_bfloat16* gA0 = xb + (size_t)(row_base + sRow) * GD + sKb * 8;
    const __hip_bfloat16* gA1 = gA0 + (size_t)64 * GD;
    const __hip_bfloat16* gB0 = xb + (size_t)(col_base + sRow) * GD + sKb * 8;
    const __hip_bfloat16* gB1 = gB0 + (size_t)64 * GD;

    int offA[2], offB[8];
#pragma unroll
    for (int ti = 0; ti < 2; ++ti) offA[ti] = swz(w * 32 + ti * 16 + cl, quad);
#pragma unroll
    for (int tj = 0; tj < 8; ++tj) offB[tj] = swz(tj * 16 + cl, quad);

    f32x4 acc[2][8];
#pragma unroll
    for (int i = 0; i < 2; ++i)
#pragma unroll
        for (int j = 0; j < 8; ++j) acc[i][j] = (f32x4){0.f, 0.f, 0.f, 0.f};

    // prologue: stage k=0 into buffer 0
    gl2lds16(gA0, As[0] + tid * 16);
    gl2lds16(gA1, As[0] + 4096 + tid * 16);
    gl2lds16(gB0, Bs[0] + tid * 16);
    gl2lds16(gB1, Bs[0] + 4096 + tid * 16);

#pragma unroll 4
    for (int kk = 0; kk < KSTEPS; ++kk) {
        __syncthreads();  // drains vmcnt: buf[kk&1] valid; prior buf reads done

        // 1) read this iter's fragments FIRST (no vm dependency -> no vm wait)
        const char* ab = As[kk & 1];
        const char* bbuf = Bs[kk & 1];
        bf16x8 af[2], bfv[8];
#pragma unroll
        for (int ti = 0; ti < 2; ++ti) af[ti] = *(const bf16x8*)(ab + offA[ti]);
#pragma unroll
        for (int tj = 0; tj < 8; ++tj) bfv[tj] = *(const bf16x8*)(bbuf + offB[tj]);

        // 2) then issue next iter's staging; it flies during the MFMA phase and
        //    is only drained at the next barrier
        if (kk + 1 < KSTEPS) {
            const int k1 = (kk + 1) * 32;  // bf16 elements
            char* a = As[(kk + 1) & 1];
            char* bs = Bs[(kk + 1) & 1];
            gl2lds16(gA0 + k1, a + tid * 16);
            gl2lds16(gA1 + k1, a + 4096 + tid * 16);
            gl2lds16(gB0 + k1, bs + tid * 16);
            gl2lds16(gB1 + k1, bs + 4096 + tid * 16);
        }

        // 3) MFMAs (depend on lgkmcnt only)
#pragma unroll
        for (int ti = 0; ti < 2; ++ti)
#pragma unroll
            for (int tj = 0; tj < 8; ++tj)
                acc[ti][tj] = __builtin_amdgcn_mfma_f32_16x16x32_bf16(
                    af[ti], bfv[tj], acc[ti][tj], 0, 0, 0);
    }

    // per-lane metadata
    float sqr[8];
    int rowg[8];
#pragma unroll
    for (int ti = 0; ti < 2; ++ti)
#pragma unroll
        for (int rg = 0; rg < 4; ++rg) {
            int r = row_base + w * 32 + ti * 16 + quad * 4 + rg;
            rowg[ti * 4 + rg] = r;
            sqr[ti * 4 + rg] = sq[r];
        }
    float sqc[8];
    int colg[8];
#pragma unroll
    for (int tj = 0; tj < 8; ++tj) {
        int c = col_base + tj * 16 + cl;
        colg[tj] = c;
        sqc[tj] = sq[c];
    }

    // ---- direct pass: one (m,S,T) per row of block I over J's 128 cols ----
#pragma unroll
    for (int ti = 0; ti < 2; ++ti)
#pragma unroll
        for (int rg = 0; rg < 4; ++rg) {
            const int idx = ti * 4 + rg;
            float vv[8];
            float mloc = -1e30f;
#pragma unroll
            for (int tj = 0; tj < 8; ++tj) {
                float pen = (rowg[idx] == colg[tj]) ? 100.f : 0.f;
                float v = tau * (2.f * acc[ti][tj][rg] - sqr[idx] - sqc[tj] - pen);
                vv[tj] = v;
                mloc = fmaxf(mloc, v);
            }
#pragma unroll
            for (int mk = 1; mk < 16; mk <<= 1) mloc = fmaxf(mloc, __shfl_xor(mloc, mk));
            float s = 0.f, t = 0.f;
#pragma unroll
            for (int tj = 0; tj < 8; ++tj) {
                float d = vv[tj] - mloc;
                float e = __expf(d);
                s += e;
                t += e * d;
            }
#pragma unroll
            for (int mk = 1; mk < 16; mk <<= 1) {
                s += __shfl_xor(s, mk);
                t += __shfl_xor(t, mk);
            }
            if (cl == 0) {
                int r = rowg[idx];
                pm[(size_t)J * GN + r] = mloc;
                ps[(size_t)J * GN + r] = s;
                pt[(size_t)J * GN + r] = t;
            }
        }

    // ---- transposed pass (off-diagonal tiles): rows of block J over I's rows ----
    if (I != J) {  // block-uniform branch
#pragma unroll
        for (int tj = 0; tj < 8; ++tj) {
            float vv[8];
            float mloc = -1e30f;
#pragma unroll
            for (int ti = 0; ti < 2; ++ti)
#pragma unroll
                for (int rg = 0; rg < 4; ++rg) {
                    float v = tau * (2.f * acc[ti][tj][rg] - sqr[ti * 4 + rg] - sqc[tj]);
                    vv[ti * 4 + rg] = v;
                    mloc = fmaxf(mloc, v);
                }
            mloc = fmaxf(mloc, __shfl_xor(mloc, 16));
            mloc = fmaxf(mloc, __shfl_xor(mloc, 32));
            float s = 0.f, t = 0.f;
#pragma unroll
            for (int k = 0; k < 8; ++k) {
                float d = vv[k] - mloc;
                float e = __expf(d);
                s += e;
                t += e * d;
            }
            s += __shfl_xor(s, 16);
            t += __shfl_xor(t, 16);
            s += __shfl_xor(s, 32);
            t += __shfl_xor(t, 32);
            if (quad == 0) {
                int c = tj * 16 + cl;
                tmrg[c][w][0] = mloc;
                tmrg[c][w][1] = s;
                tmrg[c][w][2] = t;
            }
        }
        __syncthreads();
        if (tid < 128) {
            float m = tmrg[tid][0][0], S = tmrg[tid][0][1], T = tmrg[tid][0][2];
#pragma unroll
            for (int ww = 1; ww < 4; ++ww) {
                float mc = tmrg[tid][ww][0], Sc = tmrg[tid][ww][1], Tc = tmrg[tid][ww][2];
                float mn = fmaxf(m, mc);
                float ea = __expf(m - mn), eb = __expf(mc - mn);
                T = (T + (m - mn) * S) * ea + (Tc + (mc - mn) * Sc) * eb;
                S = S * ea + Sc * eb;
                m = mn;
            }
            int c = col_base + tid;
            pm[(size_t)I * GN + c] = m;
            ps[(size_t)I * GN + c] = S;
            pt[(size_t)I * GN + c] = T;
        }
    }
}

// ---------------- Kernel 3: combine 64 slots -> row entropy -> atomic scalar ----------------
__global__ __launch_bounds__(256) void combine(const float* __restrict__ pm,
                                               const float* __restrict__ ps,
                                               const float* __restrict__ pt,
                                               const float* __restrict__ coefp,
                                               float* __restrict__ out) {
    const int row = blockIdx.x * 256 + threadIdx.x;
    float m = -1e30f, S = 0.f, T = 0.f;
    for (int c = 0; c < NB; ++c) {
        float mc = pm[(size_t)c * GN + row];
        float Sc = ps[(size_t)c * GN + row];
        float Tc = pt[(size_t)c * GN + row];
        float mn = fmaxf(m, mc);
        float ea = __expf(m - mn), eb = __expf(mc - mn);
        T = (T + (m - mn) * S) * ea + (Tc + (mc - mn) * Sc) * eb;
        S = S * ea + Sc * eb;
        m = mn;
    }
    float ent = __logf(S) - T / S;
#pragma unroll
    for (int off = 1; off < 64; off <<= 1) ent += __shfl_xor(ent, off);
    __shared__ float ls[4];
    if ((threadIdx.x & 63) == 0) ls[threadIdx.x >> 6] = ent;
    __syncthreads();
    if (threadIdx.x == 0)
        atomicAdd(out, (ls[0] + ls[1] + ls[2] + ls[3]) * coefp[0] * (1.0f / (float)GN));
}

extern "C" void kernel_launch(void* const* d_in, const int* in_sizes, int n_in,
                              void* d_out, int out_size, void* d_ws, size_t ws_size,
                              hipStream_t stream) {
    const float* x = (const float*)d_in[0];      // 8192*768 fp32
    const float* coefp = (const float*)d_in[1];  // scalar
    const float* taup = (const float*)d_in[2];   // scalar
    float* out = (float*)d_out;

    char* ws = (char*)d_ws;
    __hip_bfloat16* xb = (__hip_bfloat16*)ws;            // 12,582,912 B
    float* sq = (float*)(ws + 12582912);                 // 32,768 B
    float* pm = (float*)(ws + 12615680);                 // 2,097,152 B
    float* ps = (float*)(ws + 12615680 + 2097152);       // 2,097,152 B
    float* pt = (float*)(ws + 12615680 + 2 * 2097152);   // 2,097,152 B

    prep_kernel<<<GN / 4, 256, 0, stream>>>(x, xb, sq, out);
    sym_gemm_entropy<<<NTILE, 256, 0, stream>>>(xb, sq, taup, pm, ps, pt);
    combine<<<GN / 256, 256, 0, stream>>>(pm, ps, pt, coefp, out);
}